// Round 9
// baseline (177.752 us; speedup 1.0000x reference)
//
#include <hip/hip_runtime.h>
#include <hip/hip_bf16.h>
#include <cstddef>

#define B_    128
#define D_    2048
#define C_    16522
#define BETA_INV 20.0f      // 1/0.05
#define LSTRIDE 16528       // padded logits row stride (floats)

#define NTILES 1033         // ceil(C/16)
#define NCHUNK 8
#define CHW    2066         // ceil(C/8)

typedef __bf16 bf16;
typedef bf16  bf16x8 __attribute__((ext_vector_type(8)));
typedef float f32x4  __attribute__((ext_vector_type(4)));

// ws layout (bytes):
//   logits : [0, 8462336)                128*16528*4
//   A_pack : [8462336, 8986624)          128*2048*2  bf16 fragment-ordered
//   part   : [8986624, 9052160)          128*8*16*4  row_loss partials
#define WS_APACK_OFF 8462336
#define WS_PART_OFF  8986624

// ---------------------------------------------------------------------------
// prep: fused pack_a + copy_em + em_update. R9.
// Blocks [0,128): pack inputs [128,2048] fp32 -> bf16 MFMA A-fragment order.
// Block 128+r: owns em row r. Unlabeled rows (99.2%): vectorized copy
// em->out_em. Labeled rows: full sequential EMA chain (bit-identical to the
// old em_update: same t+u*256 ownership, same shfl/LDS reduction) then write.
// Runs FIRST: its em read warms the memory-side L3 so gemm runs warm
// (~20-25 µs vs 80 cold — R6/R7 A/B). Every cold-em-streaming kernel tried
// (3 hand copies, AMD blit, 3 fused gemms) caps at 2.0-2.6 TB/s — the cap is
// environmental (reset leaves L3 full of dirty lines), so we stop fighting
// it and minimize serial launches around it instead.
// ---------------------------------------------------------------------------
__global__ __launch_bounds__(256) void prep(
    const float* __restrict__ inp,
    const int*   __restrict__ label,
    const float* __restrict__ em,
    const int*   __restrict__ epoch,
    bf16*        __restrict__ ap,
    float*       __restrict__ out_em)
{
  const int t = threadIdx.x;
  const int b = blockIdx.x;

  if (b < 128) {                       // ---- pack_a ----
    const int tid  = b * 256 + t;      // 0..32767
    const int lane = tid & 63;
    const int ks   = (tid >> 6) & 63;
    const int mt   = tid >> 12;
    const int row  = mt * 16 + (lane & 15);
    const int col  = ks * 32 + (lane >> 4) * 8;
    const float4 v0 = *(const float4*)(inp + row * D_ + col);
    const float4 v1 = *(const float4*)(inp + row * D_ + col + 4);
    bf16x8 bb;
    bb[0] = (bf16)v0.x; bb[1] = (bf16)v0.y; bb[2] = (bf16)v0.z; bb[3] = (bf16)v0.w;
    bb[4] = (bf16)v1.x; bb[5] = (bf16)v1.y; bb[6] = (bf16)v1.z; bb[7] = (bf16)v1.w;
    ((bf16x8*)ap)[tid] = bb;
    return;                            // whole block uniform
  }

  const int r = b - 128;               // em row 0..16521
  __shared__ int   lbl[B_];
  __shared__ float red[4];
  if (t < B_) lbl[t] = label[t];
  __syncthreads();

  int i0 = -1;                         // first sample with label == r
  for (int j = 0; j < B_; ++j)
    if (lbl[j] == r) { i0 = j; break; }   // uniform across block

  if (i0 < 0) {                        // ---- plain copy row ----
    const f32x4* src = (const f32x4*)(em + (size_t)r * D_);
    float*       dst = out_em + (size_t)r * D_;
    const f32x4 v0 = src[t * 2];
    const f32x4 v1 = src[t * 2 + 1];
    *(f32x4*)(dst + t * 8)     = v0;
    *(f32x4*)(dst + t * 8 + 4) = v1;
    return;
  }

  // ---- EMA chain for labeled row (exact old em_update math) ----
  const float alpha = 0.01f * (float)epoch[0];
  const int lane = t & 63, wave = t >> 6;

  float rr[8];
  #pragma unroll
  for (int u = 0; u < 8; ++u) rr[u] = em[(size_t)r * D_ + t + u * 256];

  for (int j = i0; j < B_; ++j) {
    if (lbl[j] != r) continue;         // uniform branch
    const float* x = inp + j * D_;
    float ss = 0.f;
    #pragma unroll
    for (int u = 0; u < 8; ++u) {
      rr[u] = alpha * rr[u] + (1.f - alpha) * x[t + u * 256];
      ss += rr[u] * rr[u];
    }
    #pragma unroll
    for (int off = 32; off >= 1; off >>= 1) ss += __shfl_down(ss, off);
    if (lane == 0) red[wave] = ss;
    __syncthreads();
    const float inv = 1.f / sqrtf(red[0] + red[1] + red[2] + red[3]);
    #pragma unroll
    for (int u = 0; u < 8; ++u) rr[u] *= inv;
    __syncthreads();                   // red[] reused next chain step
  }

  #pragma unroll
  for (int u = 0; u < 8; ++u) out_em[(size_t)r * D_ + t + u * 256] = rr[u];
}

// ---------------------------------------------------------------------------
// gemm: 4 waves per block, one 16-row n-tile of em per block, in-block
// split-K (wave w owns k-steps [w*16, w*16+16)). No stores in the inner
// loop; writes only logits. Runs after prep: em L3-warm -> ~20-25 µs
// (80 µs cold, R7 measured).
// ---------------------------------------------------------------------------
__global__ __launch_bounds__(256, 4) void gemm_logits(
    const bf16*  __restrict__ ap,
    const float* __restrict__ em,
    float*       __restrict__ logits)
{
  const int tid  = threadIdx.x;
  const int lane = tid & 63;
  const int w    = tid >> 6;          // K-quarter 0..3
  const int ml   = lane & 15;
  const int quad = lane >> 4;
  const int n0   = blockIdx.x * 16;
  const int r    = n0 + ml;
  const bool valid = r < C_;

  const float* bp = em + (size_t)(valid ? r : 0) * D_ + quad * 8;
  const bf16x8* af = (const bf16x8*)ap;

  const int ks0 = w * 16;

  f32x4 acc[8] = {};

  // prologue: em chunk for first iteration in flight
  f32x4 e0a = *(const f32x4*)(bp + ks0 * 32);
  f32x4 e0b = *(const f32x4*)(bp + ks0 * 32 + 4);

  #pragma unroll 3
  for (int i = 0; i < 15; ++i) {
    const int ks = ks0 + i;
    // A frags for THIS iteration (L2-resident)
    bf16x8 A0[8];
    #pragma unroll
    for (int mt = 0; mt < 8; ++mt)
      A0[mt] = af[(mt * 64 + ks) * 64 + lane];
    // em prefetch for NEXT iteration (L3-warm)
    const f32x4 e1a = *(const f32x4*)(bp + (ks + 1) * 32);
    const f32x4 e1b = *(const f32x4*)(bp + (ks + 1) * 32 + 4);
    // consume
    bf16x8 bv;
    bv[0] = (bf16)e0a[0]; bv[1] = (bf16)e0a[1]; bv[2] = (bf16)e0a[2]; bv[3] = (bf16)e0a[3];
    bv[4] = (bf16)e0b[0]; bv[5] = (bf16)e0b[1]; bv[6] = (bf16)e0b[2]; bv[7] = (bf16)e0b[3];
    #pragma unroll
    for (int mt = 0; mt < 8; ++mt)
      acc[mt] = __builtin_amdgcn_mfma_f32_16x16x32_bf16(A0[mt], bv, acc[mt], 0, 0, 0);
    e0a = e1a; e0b = e1b;
  }
  // epilogue: iteration 15
  {
    const int ks = ks0 + 15;
    bf16x8 A0[8];
    #pragma unroll
    for (int mt = 0; mt < 8; ++mt)
      A0[mt] = af[(mt * 64 + ks) * 64 + lane];
    bf16x8 bv;
    bv[0] = (bf16)e0a[0]; bv[1] = (bf16)e0a[1]; bv[2] = (bf16)e0a[2]; bv[3] = (bf16)e0a[3];
    bv[4] = (bf16)e0b[0]; bv[5] = (bf16)e0b[1]; bv[6] = (bf16)e0b[2]; bv[7] = (bf16)e0b[3];
    #pragma unroll
    for (int mt = 0; mt < 8; ++mt)
      acc[mt] = __builtin_amdgcn_mfma_f32_16x16x32_bf16(A0[mt], bv, acc[mt], 0, 0, 0);
  }

  // combine the 4 K-partials through LDS; wave 0 writes logits
  __shared__ f32x4 red[3][8][64];     // 24 KB
  if (w > 0) {
    #pragma unroll
    for (int mt = 0; mt < 8; ++mt) red[w - 1][mt][lane] = acc[mt];
  }
  __syncthreads();
  if (w == 0 && valid) {
    #pragma unroll
    for (int mt = 0; mt < 8; ++mt) {
      f32x4 a = acc[mt];
      a += red[0][mt][lane];
      a += red[1][mt][lane];
      a += red[2][mt][lane];
      #pragma unroll
      for (int reg = 0; reg < 4; ++reg) {
        const int row = mt * 16 + quad * 4 + reg;
        logits[row * LSTRIDE + r] = a[reg] * BETA_INV;
      }
    }
  }
}

// ---------------------------------------------------------------------------
// row_loss phase A: grid = 128 rows x 8 chunks. Partial online-lse + top-6
// + label logit per chunk -> part[(b*8+c)*16].
// ---------------------------------------------------------------------------
__global__ __launch_bounds__(256) void row_loss_part(
    const float* __restrict__ logits,
    const int*   __restrict__ label,
    float*       __restrict__ part)
{
  const int b = blockIdx.x >> 3;
  const int c = blockIdx.x & 7;
  const int t = threadIdx.x;
  const int lo = c * CHW;
  const int hi = (lo + CHW < C_) ? lo + CHW : C_;
  const float* row = logits + b * LSTRIDE;
  const int y = label[b];

  float m = -INFINITY, s = 0.f, ly = -INFINITY;
  float tv[6]; int ti[6];
  #pragma unroll
  for (int q = 0; q < 6; ++q) { tv[q] = -INFINITY; ti[q] = -1; }

  for (int i = lo + t; i < hi; i += 256) {
    const float v = row[i];
    if (v > m) { s = s * __expf(m - v) + 1.f; m = v; }
    else       { s += __expf(v - m); }
    if (i == y) ly = v;
    if (v > tv[5]) {
      tv[5] = v; ti[5] = i;
      #pragma unroll
      for (int q = 5; q > 0; --q)
        if (tv[q] > tv[q - 1]) {
          const float fv = tv[q]; tv[q] = tv[q - 1]; tv[q - 1] = fv;
          const int   fi = ti[q]; ti[q] = ti[q - 1]; ti[q - 1] = fi;
        }
    }
  }

  __shared__ float rm[256], rs[256];
  __shared__ float cv[1536];
  __shared__ int   ci[1536];
  __shared__ float sly;

  rm[t] = m; rs[t] = s;
  #pragma unroll
  for (int q = 0; q < 6; ++q) { cv[t * 6 + q] = tv[q]; ci[t * 6 + q] = ti[q]; }
  if (t == 0) sly = -INFINITY;
  __syncthreads();
  if (ly != -INFINITY) sly = ly;

  for (int off = 128; off >= 1; off >>= 1) {
    if (t < off) {
      const float m2 = rm[t + off], s2 = rs[t + off];
      const float M = fmaxf(rm[t], m2);
      rs[t] = rs[t] * __expf(rm[t] - M) + s2 * __expf(m2 - M);
      rm[t] = M;
    }
    __syncthreads();
  }

  if (t < 64) {   // wave 0: top-6 of 1536 candidates
    float otv[6]; int oti[6];
    for (int rr = 0; rr < 6; ++rr) {
      float bv = -INFINITY; int bi = -1, bs = -1;
      for (int u = 0; u < 24; ++u) {
        const int slot = t * 24 + u;
        const float v = cv[slot];
        if (v > bv) { bv = v; bi = ci[slot]; bs = slot; }
      }
      #pragma unroll
      for (int off = 32; off >= 1; off >>= 1) {
        const float ov = __shfl_down(bv, off);
        const int   oi = __shfl_down(bi, off);
        const int   os = __shfl_down(bs, off);
        if (ov > bv) { bv = ov; bi = oi; bs = os; }
      }
      bv = __shfl(bv, 0); bi = __shfl(bi, 0); bs = __shfl(bs, 0);
      if (bs >= t * 24 && bs < (t + 1) * 24) cv[bs] = -INFINITY;
      otv[rr] = bv; oti[rr] = bi;
    }
    if (t == 0) {
      float* p = part + (size_t)(b * 8 + c) * 16;
      p[0] = rm[0]; p[1] = rs[0]; p[2] = sly;
      #pragma unroll
      for (int q = 0; q < 6; ++q) { p[4 + q] = otv[q]; ((int*)p)[10 + q] = oti[q]; }
    }
  }
}

// ---------------------------------------------------------------------------
// row_loss merge: 128 blocks x 64 threads. Merge 8 chunk-partials, compute
// loss, atomicAdd into out[0].
// ---------------------------------------------------------------------------
__global__ __launch_bounds__(64) void row_loss_merge(
    const float* __restrict__ part,
    const int*   __restrict__ label,
    float*       __restrict__ out)
{
  const int b = blockIdx.x;
  const int lane = threadIdx.x;
  const int y = label[b];

  float m = -INFINITY, s = 0.f, ly = -INFINITY;
  if (lane < 8) {
    const float* p = part + (size_t)(b * 8 + lane) * 16;
    m = p[0]; s = p[1]; ly = p[2];
  }
  float M = m, LY = ly;
  #pragma unroll
  for (int off = 32; off >= 1; off >>= 1) {
    M  = fmaxf(M,  __shfl_down(M,  off));
    LY = fmaxf(LY, __shfl_down(LY, off));
  }
  M = __shfl(M, 0); LY = __shfl(LY, 0);
  float contrib = (lane < 8) ? s * __expf(m - M) : 0.f;
  #pragma unroll
  for (int off = 32; off >= 1; off >>= 1) contrib += __shfl_down(contrib, off);
  const float S = __shfl(contrib, 0);

  float v = -INFINITY; int idx = -1;
  if (lane < 48) {
    const float* p = part + (size_t)(b * 8 + lane / 6) * 16;
    v   = p[4 + lane % 6];
    idx = ((const int*)p)[10 + lane % 6];
  }
  float stop = 0.f; int intop = 0;
  for (int rr = 0; rr < 6; ++rr) {
    float bv = v; int bi = idx, bl = lane;
    #pragma unroll
    for (int off = 32; off >= 1; off >>= 1) {
      const float ov = __shfl_down(bv, off);
      const int   oi = __shfl_down(bi, off);
      const int   ol = __shfl_down(bl, off);
      if (ov > bv) { bv = ov; bi = oi; bl = ol; }
    }
    bv = __shfl(bv, 0); bi = __shfl(bi, 0); bl = __shfl(bl, 0);
    stop += bv;
    if (bi == y) intop = 1;
    if (lane == bl) v = -INFINITY;
  }

  if (lane == 0) {
    const float lse = M + logf(S);
    const float loss = intop ? (13.f * lse - LY - 2.f * stop)
                             : (15.f * lse - 3.f * LY - 2.f * stop);
    atomicAdd(out, loss * (1.0f / 128.0f));
  }
}

// ---------------------------------------------------------------------------
// R9 pipeline: prep (copy+em_update+pack, warms em) -> gemm (warm) ->
// row_loss_part -> row_loss_merge.
// ---------------------------------------------------------------------------
extern "C" void kernel_launch(void* const* d_in, const int* in_sizes, int n_in,
                              void* d_out, int out_size, void* d_ws, size_t ws_size,
                              hipStream_t stream) {
  const float* inp   = (const float*)d_in[0];
  const int*   label = (const int*)d_in[1];
  const float* em    = (const float*)d_in[2];
  const int*   epoch = (const int*)d_in[3];

  float* out    = (float*)d_out;
  float* out_em = out + 1;
  float* logits = (float*)d_ws;
  bf16*  apack  = (bf16*)((char*)d_ws + WS_APACK_OFF);
  float* part   = (float*)((char*)d_ws + WS_PART_OFF);

  hipMemsetAsync(d_out, 0, sizeof(float), stream);   // zero the loss slot

  prep          <<<dim3(128 + C_),   dim3(256), 0, stream>>>(inp, label, em, epoch, apack, out_em);
  gemm_logits   <<<dim3(NTILES),     dim3(256), 0, stream>>>(apack, em, logits);
  row_loss_part <<<dim3(B_ * NCHUNK),dim3(256), 0, stream>>>(logits, label, part);
  row_loss_merge<<<dim3(B_),         dim3(64),  0, stream>>>(part, label, out);
}

// Round 10
// 128.337 us; speedup vs baseline: 1.3850x; 1.3850x over previous
//
#include <hip/hip_runtime.h>
#include <hip/hip_bf16.h>
#include <cstddef>

#define B_    128
#define D_    2048
#define C_    16522
#define BETA_INV 20.0f      // 1/0.05
#define LSTRIDE 16528       // padded logits row stride (floats)

#define NTILES 1033         // ceil(C/16)
#define NCHUNK 8
#define CHW    2066         // ceil(C/8)

typedef __bf16 bf16;
typedef bf16  bf16x8 __attribute__((ext_vector_type(8)));
typedef float f32x4  __attribute__((ext_vector_type(4)));

// ws layout (bytes):
//   logits : [0, 8462336)                128*16528*4
//   A_pack : [8462336, 8986624)          128*2048*2  bf16 fragment-ordered
//   part   : [8986624, 9052160)          128*8*16*4  row_loss partials
#define WS_APACK_OFF 8462336
#define WS_PART_OFF  8986624

// ---------------------------------------------------------------------------
// copy_pack: R10 = R5's proven copy_em (77 µs) + pack_a fused as the first
// 128 blocks. Copy body is byte-identical to R5/R6 (2048 grid-stride blocks,
// 2x unrolled float4). Pack blocks are 0.5% of the work and ride free,
// saving pack_a's ~8 µs serial launch. R9's lesson: do NOT add per-block
// label logic to the stream (serial scan cost +32 µs, VALUBusy 42%).
// Cold-stream wall: every implementation (3 hand copies, AMD blit, fused
// gemms) caps at 2.0-2.6 TB/s while pure writes hit 7 TB/s — environmental
// (reset leaves L3 dirty); we stream once and keep everything else warm.
// ---------------------------------------------------------------------------
__global__ __launch_bounds__(256) void copy_pack(
    const float* __restrict__ em,
    float*       __restrict__ out_em,
    const float* __restrict__ inp,
    bf16*        __restrict__ ap)
{
  const int t = threadIdx.x;
  const int b = blockIdx.x;

  if (b < 128) {                       // ---- pack_a ----
    const int tid  = b * 256 + t;      // 0..32767
    const int lane = tid & 63;
    const int ks   = (tid >> 6) & 63;
    const int mt   = tid >> 12;
    const int row  = mt * 16 + (lane & 15);
    const int col  = ks * 32 + (lane >> 4) * 8;
    const float4 v0 = *(const float4*)(inp + row * D_ + col);
    const float4 v1 = *(const float4*)(inp + row * D_ + col + 4);
    bf16x8 bb;
    bb[0] = (bf16)v0.x; bb[1] = (bf16)v0.y; bb[2] = (bf16)v0.z; bb[3] = (bf16)v0.w;
    bb[4] = (bf16)v1.x; bb[5] = (bf16)v1.y; bb[6] = (bf16)v1.z; bb[7] = (bf16)v1.w;
    ((bf16x8*)ap)[tid] = bb;
    return;                            // whole block uniform
  }

  // ---- copy_em (R5 body, 2048 blocks) ----
  const int cb = b - 128;
  const size_t n = (size_t)C_ * D_ / 4;          // 8,459,264 float4
  const size_t stride = (size_t)2048 * 512;
  for (size_t i = (size_t)cb * 512 + t; i < n; i += stride) {
    const f32x4 v0 = ((const f32x4*)em)[i];
    const bool  h1 = (i + 256) < n;
    f32x4 v1 = {};
    if (h1) v1 = ((const f32x4*)em)[i + 256];
    ((f32x4*)out_em)[i] = v0;
    if (h1) ((f32x4*)out_em)[i + 256] = v1;
  }
}

// ---------------------------------------------------------------------------
// gemm: 4 waves per block, one 16-row n-tile of em per block, in-block
// split-K (wave w owns k-steps [w*16, w*16+16)). No stores in the inner
// loop; writes only logits. Runs after copy_pack: em L3-warm -> ~25 µs
// (80 µs cold, R7 measured).
// ---------------------------------------------------------------------------
__global__ __launch_bounds__(256, 4) void gemm_logits(
    const bf16*  __restrict__ ap,
    const float* __restrict__ em,
    float*       __restrict__ logits)
{
  const int tid  = threadIdx.x;
  const int lane = tid & 63;
  const int w    = tid >> 6;          // K-quarter 0..3
  const int ml   = lane & 15;
  const int quad = lane >> 4;
  const int n0   = blockIdx.x * 16;
  const int r    = n0 + ml;
  const bool valid = r < C_;

  const float* bp = em + (size_t)(valid ? r : 0) * D_ + quad * 8;
  const bf16x8* af = (const bf16x8*)ap;

  const int ks0 = w * 16;

  f32x4 acc[8] = {};

  // prologue: em chunk for first iteration in flight
  f32x4 e0a = *(const f32x4*)(bp + ks0 * 32);
  f32x4 e0b = *(const f32x4*)(bp + ks0 * 32 + 4);

  #pragma unroll 3
  for (int i = 0; i < 15; ++i) {
    const int ks = ks0 + i;
    // A frags for THIS iteration (L2-resident)
    bf16x8 A0[8];
    #pragma unroll
    for (int mt = 0; mt < 8; ++mt)
      A0[mt] = af[(mt * 64 + ks) * 64 + lane];
    // em prefetch for NEXT iteration (L3-warm)
    const f32x4 e1a = *(const f32x4*)(bp + (ks + 1) * 32);
    const f32x4 e1b = *(const f32x4*)(bp + (ks + 1) * 32 + 4);
    // consume
    bf16x8 bv;
    bv[0] = (bf16)e0a[0]; bv[1] = (bf16)e0a[1]; bv[2] = (bf16)e0a[2]; bv[3] = (bf16)e0a[3];
    bv[4] = (bf16)e0b[0]; bv[5] = (bf16)e0b[1]; bv[6] = (bf16)e0b[2]; bv[7] = (bf16)e0b[3];
    #pragma unroll
    for (int mt = 0; mt < 8; ++mt)
      acc[mt] = __builtin_amdgcn_mfma_f32_16x16x32_bf16(A0[mt], bv, acc[mt], 0, 0, 0);
    e0a = e1a; e0b = e1b;
  }
  // epilogue: iteration 15
  {
    const int ks = ks0 + 15;
    bf16x8 A0[8];
    #pragma unroll
    for (int mt = 0; mt < 8; ++mt)
      A0[mt] = af[(mt * 64 + ks) * 64 + lane];
    bf16x8 bv;
    bv[0] = (bf16)e0a[0]; bv[1] = (bf16)e0a[1]; bv[2] = (bf16)e0a[2]; bv[3] = (bf16)e0a[3];
    bv[4] = (bf16)e0b[0]; bv[5] = (bf16)e0b[1]; bv[6] = (bf16)e0b[2]; bv[7] = (bf16)e0b[3];
    #pragma unroll
    for (int mt = 0; mt < 8; ++mt)
      acc[mt] = __builtin_amdgcn_mfma_f32_16x16x32_bf16(A0[mt], bv, acc[mt], 0, 0, 0);
  }

  // combine the 4 K-partials through LDS; wave 0 writes logits
  __shared__ f32x4 red[3][8][64];     // 24 KB
  if (w > 0) {
    #pragma unroll
    for (int mt = 0; mt < 8; ++mt) red[w - 1][mt][lane] = acc[mt];
  }
  __syncthreads();
  if (w == 0 && valid) {
    #pragma unroll
    for (int mt = 0; mt < 8; ++mt) {
      f32x4 a = acc[mt];
      a += red[0][mt][lane];
      a += red[1][mt][lane];
      a += red[2][mt][lane];
      #pragma unroll
      for (int reg = 0; reg < 4; ++reg) {
        const int row = mt * 16 + quad * 4 + reg;
        logits[row * LSTRIDE + r] = a[reg] * BETA_INV;
      }
    }
  }
}

// ---------------------------------------------------------------------------
// row_loss phase A: grid = 128 rows x 8 chunks. Partial online-lse + top-6
// + label logit per chunk -> part[(b*8+c)*16].
// ---------------------------------------------------------------------------
__global__ __launch_bounds__(256) void row_loss_part(
    const float* __restrict__ logits,
    const int*   __restrict__ label,
    float*       __restrict__ part)
{
  const int b = blockIdx.x >> 3;
  const int c = blockIdx.x & 7;
  const int t = threadIdx.x;
  const int lo = c * CHW;
  const int hi = (lo + CHW < C_) ? lo + CHW : C_;
  const float* row = logits + b * LSTRIDE;
  const int y = label[b];

  float m = -INFINITY, s = 0.f, ly = -INFINITY;
  float tv[6]; int ti[6];
  #pragma unroll
  for (int q = 0; q < 6; ++q) { tv[q] = -INFINITY; ti[q] = -1; }

  for (int i = lo + t; i < hi; i += 256) {
    const float v = row[i];
    if (v > m) { s = s * __expf(m - v) + 1.f; m = v; }
    else       { s += __expf(v - m); }
    if (i == y) ly = v;
    if (v > tv[5]) {
      tv[5] = v; ti[5] = i;
      #pragma unroll
      for (int q = 5; q > 0; --q)
        if (tv[q] > tv[q - 1]) {
          const float fv = tv[q]; tv[q] = tv[q - 1]; tv[q - 1] = fv;
          const int   fi = ti[q]; ti[q] = ti[q - 1]; ti[q - 1] = fi;
        }
    }
  }

  __shared__ float rm[256], rs[256];
  __shared__ float cv[1536];
  __shared__ int   ci[1536];
  __shared__ float sly;

  rm[t] = m; rs[t] = s;
  #pragma unroll
  for (int q = 0; q < 6; ++q) { cv[t * 6 + q] = tv[q]; ci[t * 6 + q] = ti[q]; }
  if (t == 0) sly = -INFINITY;
  __syncthreads();
  if (ly != -INFINITY) sly = ly;

  for (int off = 128; off >= 1; off >>= 1) {
    if (t < off) {
      const float m2 = rm[t + off], s2 = rs[t + off];
      const float M = fmaxf(rm[t], m2);
      rs[t] = rs[t] * __expf(rm[t] - M) + s2 * __expf(m2 - M);
      rm[t] = M;
    }
    __syncthreads();
  }

  if (t < 64) {   // wave 0: top-6 of 1536 candidates
    float otv[6]; int oti[6];
    for (int rr = 0; rr < 6; ++rr) {
      float bv = -INFINITY; int bi = -1, bs = -1;
      for (int u = 0; u < 24; ++u) {
        const int slot = t * 24 + u;
        const float v = cv[slot];
        if (v > bv) { bv = v; bi = ci[slot]; bs = slot; }
      }
      #pragma unroll
      for (int off = 32; off >= 1; off >>= 1) {
        const float ov = __shfl_down(bv, off);
        const int   oi = __shfl_down(bi, off);
        const int   os = __shfl_down(bs, off);
        if (ov > bv) { bv = ov; bi = oi; bs = os; }
      }
      bv = __shfl(bv, 0); bi = __shfl(bi, 0); bs = __shfl(bs, 0);
      if (bs >= t * 24 && bs < (t + 1) * 24) cv[bs] = -INFINITY;
      otv[rr] = bv; oti[rr] = bi;
    }
    if (t == 0) {
      float* p = part + (size_t)(b * 8 + c) * 16;
      p[0] = rm[0]; p[1] = rs[0]; p[2] = sly;
      #pragma unroll
      for (int q = 0; q < 6; ++q) { p[4 + q] = otv[q]; ((int*)p)[10 + q] = oti[q]; }
    }
  }
}

// ---------------------------------------------------------------------------
// row_loss merge: 128 blocks x 64 threads. Merge 8 chunk-partials, compute
// loss, atomicAdd into out[0].
// ---------------------------------------------------------------------------
__global__ __launch_bounds__(64) void row_loss_merge(
    const float* __restrict__ part,
    const int*   __restrict__ label,
    float*       __restrict__ out)
{
  const int b = blockIdx.x;
  const int lane = threadIdx.x;
  const int y = label[b];

  float m = -INFINITY, s = 0.f, ly = -INFINITY;
  if (lane < 8) {
    const float* p = part + (size_t)(b * 8 + lane) * 16;
    m = p[0]; s = p[1]; ly = p[2];
  }
  float M = m, LY = ly;
  #pragma unroll
  for (int off = 32; off >= 1; off >>= 1) {
    M  = fmaxf(M,  __shfl_down(M,  off));
    LY = fmaxf(LY, __shfl_down(LY, off));
  }
  M = __shfl(M, 0); LY = __shfl(LY, 0);
  float contrib = (lane < 8) ? s * __expf(m - M) : 0.f;
  #pragma unroll
  for (int off = 32; off >= 1; off >>= 1) contrib += __shfl_down(contrib, off);
  const float S = __shfl(contrib, 0);

  float v = -INFINITY; int idx = -1;
  if (lane < 48) {
    const float* p = part + (size_t)(b * 8 + lane / 6) * 16;
    v   = p[4 + lane % 6];
    idx = ((const int*)p)[10 + lane % 6];
  }
  float stop = 0.f; int intop = 0;
  for (int rr = 0; rr < 6; ++rr) {
    float bv = v; int bi = idx, bl = lane;
    #pragma unroll
    for (int off = 32; off >= 1; off >>= 1) {
      const float ov = __shfl_down(bv, off);
      const int   oi = __shfl_down(bi, off);
      const int   ol = __shfl_down(bl, off);
      if (ov > bv) { bv = ov; bi = oi; bl = ol; }
    }
    bv = __shfl(bv, 0); bi = __shfl(bi, 0); bl = __shfl(bl, 0);
    stop += bv;
    if (bi == y) intop = 1;
    if (lane == bl) v = -INFINITY;
  }

  if (lane == 0) {
    const float lse = M + logf(S);
    const float loss = intop ? (13.f * lse - LY - 2.f * stop)
                             : (15.f * lse - 3.f * LY - 2.f * stop);
    atomicAdd(out, loss * (1.0f / 128.0f));
  }
}

// ---------------------------------------------------------------------------
// em_update: labels staged to LDS. Block i acts only if i is the first
// occurrence of label[i]; walks the duplicate chain sequentially (exact fp32).
// Runs last (overwrites the copy's <=128 labeled rows). em rows are L3-hot.
// ---------------------------------------------------------------------------
__global__ __launch_bounds__(256) void em_update(
    const float* __restrict__ inp,
    const int*   __restrict__ label,
    const float* __restrict__ em,
    const int*   __restrict__ epoch,
    float*       __restrict__ out_em)
{
  __shared__ int lbl[B_];
  __shared__ float red[4];
  const int t = threadIdx.x;
  if (t < B_) lbl[t] = label[t];
  __syncthreads();

  const int i = blockIdx.x;
  const int y = lbl[i];
  for (int j = 0; j < i; ++j)
    if (lbl[j] == y) return;            // uniform: all threads agree

  const float alpha = 0.01f * (float)epoch[0];
  const int lane = t & 63, wave = t >> 6;

  float r[8];
  #pragma unroll
  for (int u = 0; u < 8; ++u) r[u] = em[(size_t)y * D_ + t + u * 256];

  for (int j = i; j < B_; ++j) {
    if (lbl[j] != y) continue;          // uniform branch
    const float* x = inp + j * D_;
    float ss = 0.f;
    #pragma unroll
    for (int u = 0; u < 8; ++u) {
      r[u] = alpha * r[u] + (1.f - alpha) * x[t + u * 256];
      ss += r[u] * r[u];
    }
    #pragma unroll
    for (int off = 32; off >= 1; off >>= 1) ss += __shfl_down(ss, off);
    if (lane == 0) red[wave] = ss;
    __syncthreads();
    const float inv = 1.f / sqrtf(red[0] + red[1] + red[2] + red[3]);
    #pragma unroll
    for (int u = 0; u < 8; ++u) r[u] *= inv;
    __syncthreads();                    // red[] reused next chain step
  }

  #pragma unroll
  for (int u = 0; u < 8; ++u) out_em[(size_t)y * D_ + t + u * 256] = r[u];
}

// ---------------------------------------------------------------------------
// R10 pipeline (= proven R6 ordering, pack fused into the copy):
// copy_pack (stream + warm em + pack) -> gemm (warm) -> row_loss_part ->
// row_loss_merge -> em_update.
// ---------------------------------------------------------------------------
extern "C" void kernel_launch(void* const* d_in, const int* in_sizes, int n_in,
                              void* d_out, int out_size, void* d_ws, size_t ws_size,
                              hipStream_t stream) {
  const float* inp   = (const float*)d_in[0];
  const int*   label = (const int*)d_in[1];
  const float* em    = (const float*)d_in[2];
  const int*   epoch = (const int*)d_in[3];

  float* out    = (float*)d_out;
  float* out_em = out + 1;
  float* logits = (float*)d_ws;
  bf16*  apack  = (bf16*)((char*)d_ws + WS_APACK_OFF);
  float* part   = (float*)((char*)d_ws + WS_PART_OFF);

  hipMemsetAsync(d_out, 0, sizeof(float), stream);   // zero the loss slot

  copy_pack     <<<dim3(128 + 2048), dim3(256), 0, stream>>>(em, out_em, inp, apack);
  gemm_logits   <<<dim3(NTILES),     dim3(256), 0, stream>>>(apack, em, logits);
  row_loss_part <<<dim3(B_ * NCHUNK),dim3(256), 0, stream>>>(logits, label, part);
  row_loss_merge<<<dim3(B_),         dim3(64),  0, stream>>>(part, label, out);
  em_update     <<<dim3(B_),         dim3(256), 0, stream>>>(inp, label, em, epoch, out_em);
}

// Round 11
// 119.054 us; speedup vs baseline: 1.4930x; 1.0780x over previous
//
#include <hip/hip_runtime.h>
#include <hip/hip_bf16.h>
#include <cstddef>

#define B_    128
#define D_    2048
#define C_    16522
#define BETA_INV 20.0f      // 1/0.05
#define LSTRIDE 16528       // padded logits row stride (floats)

#define NTILES 1033         // ceil(C/16)
#define NCHUNK 8
#define CHW    2066         // ceil(C/8)

#define NCOPY  2066         // copy workers in fused_main (2 per 3 blocks)
#define NFUSED 3099         // 2066 copy + 1033 gemm, interleaved 2:1

typedef __bf16 bf16;
typedef bf16  bf16x8 __attribute__((ext_vector_type(8)));
typedef float f32x4  __attribute__((ext_vector_type(4)));

// ws layout (bytes):
//   logits : [0, 8462336)                128*16528*4
//   A_pack : [8462336, 8986624)          128*2048*2  bf16 fragment-ordered
//   part   : [8986624, 9052160)          128*8*16*4  row_loss partials
#define WS_APACK_OFF 8462336
#define WS_PART_OFF  8986624

// ---------------------------------------------------------------------------
// pack_a: inputs [128,2048] fp32 -> bf16 in MFMA A-fragment order. Separate
// launch again (R11): gemm reads apack inside fused_main, so packing cannot
// share that kernel (intra-kernel race). Costs ~1-2 µs (R6->R10 delta).
// ---------------------------------------------------------------------------
__global__ __launch_bounds__(256) void pack_a(const float* __restrict__ inp,
                                              bf16* __restrict__ ap) {
  const int tid  = blockIdx.x * 256 + threadIdx.x;   // 0..32767
  const int lane = tid & 63;
  const int ks   = (tid >> 6) & 63;
  const int mt   = tid >> 12;
  const int row  = mt * 16 + (lane & 15);
  const int col  = ks * 32 + (lane >> 4) * 8;
  const float4 v0 = *(const float4*)(inp + row * D_ + col);
  const float4 v1 = *(const float4*)(inp + row * D_ + col + 4);
  bf16x8 b;
  b[0] = (bf16)v0.x; b[1] = (bf16)v0.y; b[2] = (bf16)v0.z; b[3] = (bf16)v0.w;
  b[4] = (bf16)v1.x; b[5] = (bf16)v1.y; b[6] = (bf16)v1.z; b[7] = (bf16)v1.w;
  ((bf16x8*)ap)[tid] = b;
}

// ---------------------------------------------------------------------------
// fused_main: copy_em + gemm_logits co-resident in ONE launch. R11.
// Roles interleaved by blockIdx%3 (0,1 -> copy worker, 2 -> gemm tile) so
// each CU gets a mix at dispatch: copy waves saturate the cold-stream BW
// wall (~2.6 TB/s, environmental — every implementation incl. AMD's blit
// caps there) while gemm waves fill the latency slack. The two roles are
// data-independent (copy: em->out_em; gemm: em,apack->logits) and share
// their em reads through L2/L3. Per-wave vmcnt queues don't mix across
// waves, so the R0-R3 fused-kernel poison does not apply.
// Copy body = R5's proven 2x-unrolled float4 stream (2066 workers).
// Gemm body = R10's unchanged warm gemm (1033 tiles).
// ---------------------------------------------------------------------------
__global__ __launch_bounds__(256, 4) void fused_main(
    const float* __restrict__ em,
    float*       __restrict__ out_em,
    const bf16*  __restrict__ ap,
    float*       __restrict__ logits)
{
  const int b  = blockIdx.x;
  const int g  = b / 3;
  const int r3 = b - g * 3;

  if (r3 < 2) {                        // ---- copy worker id = g*2+r3 ----
    const int id = g * 2 + r3;
    const int t  = threadIdx.x;
    const size_t n = (size_t)C_ * D_ / 4;          // 8,459,264 float4
    const size_t stride = (size_t)NCOPY * 512;
    for (size_t i = (size_t)id * 512 + t; i < n; i += stride) {
      const f32x4 v0 = ((const f32x4*)em)[i];
      const bool  h1 = (i + 256) < n;
      f32x4 v1 = {};
      if (h1) v1 = ((const f32x4*)em)[i + 256];
      ((f32x4*)out_em)[i] = v0;
      if (h1) ((f32x4*)out_em)[i + 256] = v1;
    }
    return;
  }

  // ---- gemm tile g (0..1032) ----
  const int tid  = threadIdx.x;
  const int lane = tid & 63;
  const int w    = tid >> 6;          // K-quarter 0..3
  const int ml   = lane & 15;
  const int quad = lane >> 4;
  const int n0   = g * 16;
  const int r    = n0 + ml;
  const bool valid = r < C_;

  const float* bp = em + (size_t)(valid ? r : 0) * D_ + quad * 8;
  const bf16x8* af = (const bf16x8*)ap;

  const int ks0 = w * 16;

  f32x4 acc[8] = {};

  f32x4 e0a = *(const f32x4*)(bp + ks0 * 32);
  f32x4 e0b = *(const f32x4*)(bp + ks0 * 32 + 4);

  #pragma unroll 3
  for (int i = 0; i < 15; ++i) {
    const int ks = ks0 + i;
    bf16x8 A0[8];
    #pragma unroll
    for (int mt = 0; mt < 8; ++mt)
      A0[mt] = af[(mt * 64 + ks) * 64 + lane];
    const f32x4 e1a = *(const f32x4*)(bp + (ks + 1) * 32);
    const f32x4 e1b = *(const f32x4*)(bp + (ks + 1) * 32 + 4);
    bf16x8 bv;
    bv[0] = (bf16)e0a[0]; bv[1] = (bf16)e0a[1]; bv[2] = (bf16)e0a[2]; bv[3] = (bf16)e0a[3];
    bv[4] = (bf16)e0b[0]; bv[5] = (bf16)e0b[1]; bv[6] = (bf16)e0b[2]; bv[7] = (bf16)e0b[3];
    #pragma unroll
    for (int mt = 0; mt < 8; ++mt)
      acc[mt] = __builtin_amdgcn_mfma_f32_16x16x32_bf16(A0[mt], bv, acc[mt], 0, 0, 0);
    e0a = e1a; e0b = e1b;
  }
  {
    const int ks = ks0 + 15;
    bf16x8 A0[8];
    #pragma unroll
    for (int mt = 0; mt < 8; ++mt)
      A0[mt] = af[(mt * 64 + ks) * 64 + lane];
    bf16x8 bv;
    bv[0] = (bf16)e0a[0]; bv[1] = (bf16)e0a[1]; bv[2] = (bf16)e0a[2]; bv[3] = (bf16)e0a[3];
    bv[4] = (bf16)e0b[0]; bv[5] = (bf16)e0b[1]; bv[6] = (bf16)e0b[2]; bv[7] = (bf16)e0b[3];
    #pragma unroll
    for (int mt = 0; mt < 8; ++mt)
      acc[mt] = __builtin_amdgcn_mfma_f32_16x16x32_bf16(A0[mt], bv, acc[mt], 0, 0, 0);
  }

  __shared__ f32x4 red[3][8][64];     // 24 KB (allocated per block; OK)
  if (w > 0) {
    #pragma unroll
    for (int mt = 0; mt < 8; ++mt) red[w - 1][mt][lane] = acc[mt];
  }
  __syncthreads();
  if (w == 0 && valid) {
    #pragma unroll
    for (int mt = 0; mt < 8; ++mt) {
      f32x4 a = acc[mt];
      a += red[0][mt][lane];
      a += red[1][mt][lane];
      a += red[2][mt][lane];
      #pragma unroll
      for (int reg = 0; reg < 4; ++reg) {
        const int row = mt * 16 + quad * 4 + reg;
        logits[row * LSTRIDE + r] = a[reg] * BETA_INV;
      }
    }
  }
}

// ---------------------------------------------------------------------------
// row_loss phase A: grid = 128 rows x 8 chunks. Partial online-lse + top-6
// + label logit per chunk -> part[(b*8+c)*16].
// ---------------------------------------------------------------------------
__global__ __launch_bounds__(256) void row_loss_part(
    const float* __restrict__ logits,
    const int*   __restrict__ label,
    float*       __restrict__ part)
{
  const int b = blockIdx.x >> 3;
  const int c = blockIdx.x & 7;
  const int t = threadIdx.x;
  const int lo = c * CHW;
  const int hi = (lo + CHW < C_) ? lo + CHW : C_;
  const float* row = logits + b * LSTRIDE;
  const int y = label[b];

  float m = -INFINITY, s = 0.f, ly = -INFINITY;
  float tv[6]; int ti[6];
  #pragma unroll
  for (int q = 0; q < 6; ++q) { tv[q] = -INFINITY; ti[q] = -1; }

  for (int i = lo + t; i < hi; i += 256) {
    const float v = row[i];
    if (v > m) { s = s * __expf(m - v) + 1.f; m = v; }
    else       { s += __expf(v - m); }
    if (i == y) ly = v;
    if (v > tv[5]) {
      tv[5] = v; ti[5] = i;
      #pragma unroll
      for (int q = 5; q > 0; --q)
        if (tv[q] > tv[q - 1]) {
          const float fv = tv[q]; tv[q] = tv[q - 1]; tv[q - 1] = fv;
          const int   fi = ti[q]; ti[q] = ti[q - 1]; ti[q - 1] = fi;
        }
    }
  }

  __shared__ float rm[256], rs[256];
  __shared__ float cv[1536];
  __shared__ int   ci[1536];
  __shared__ float sly;

  rm[t] = m; rs[t] = s;
  #pragma unroll
  for (int q = 0; q < 6; ++q) { cv[t * 6 + q] = tv[q]; ci[t * 6 + q] = ti[q]; }
  if (t == 0) sly = -INFINITY;
  __syncthreads();
  if (ly != -INFINITY) sly = ly;

  for (int off = 128; off >= 1; off >>= 1) {
    if (t < off) {
      const float m2 = rm[t + off], s2 = rs[t + off];
      const float M = fmaxf(rm[t], m2);
      rs[t] = rs[t] * __expf(rm[t] - M) + s2 * __expf(m2 - M);
      rm[t] = M;
    }
    __syncthreads();
  }

  if (t < 64) {   // wave 0: top-6 of 1536 candidates
    float otv[6]; int oti[6];
    for (int rr = 0; rr < 6; ++rr) {
      float bv = -INFINITY; int bi = -1, bs = -1;
      for (int u = 0; u < 24; ++u) {
        const int slot = t * 24 + u;
        const float v = cv[slot];
        if (v > bv) { bv = v; bi = ci[slot]; bs = slot; }
      }
      #pragma unroll
      for (int off = 32; off >= 1; off >>= 1) {
        const float ov = __shfl_down(bv, off);
        const int   oi = __shfl_down(bi, off);
        const int   os = __shfl_down(bs, off);
        if (ov > bv) { bv = ov; bi = oi; bs = os; }
      }
      bv = __shfl(bv, 0); bi = __shfl(bi, 0); bs = __shfl(bs, 0);
      if (bs >= t * 24 && bs < (t + 1) * 24) cv[bs] = -INFINITY;
      otv[rr] = bv; oti[rr] = bi;
    }
    if (t == 0) {
      float* p = part + (size_t)(b * 8 + c) * 16;
      p[0] = rm[0]; p[1] = rs[0]; p[2] = sly;
      #pragma unroll
      for (int q = 0; q < 6; ++q) { p[4 + q] = otv[q]; ((int*)p)[10 + q] = oti[q]; }
    }
  }
}

// ---------------------------------------------------------------------------
// tail: fused row_loss_merge (blocks 0..127) + em_update (blocks 128..255).
// Independent outputs (out[0] vs out_em rows); both depend only on kernels
// already complete. Saves one launch boundary.
// ---------------------------------------------------------------------------
__global__ __launch_bounds__(256) void tail(
    const float* __restrict__ part,
    const int*   __restrict__ label,
    float*       __restrict__ out,
    const float* __restrict__ inp,
    const float* __restrict__ em,
    const int*   __restrict__ epoch,
    float*       __restrict__ out_em)
{
  __shared__ int   lbl[B_];
  __shared__ float red[4];

  if (blockIdx.x < 128) {              // ---- row_loss_merge ----
    const int b = blockIdx.x;
    const int lane = threadIdx.x;
    if (lane >= 64) return;
    const int y = label[b];

    float m = -INFINITY, s = 0.f, ly = -INFINITY;
    if (lane < 8) {
      const float* p = part + (size_t)(b * 8 + lane) * 16;
      m = p[0]; s = p[1]; ly = p[2];
    }
    float M = m, LY = ly;
    #pragma unroll
    for (int off = 32; off >= 1; off >>= 1) {
      M  = fmaxf(M,  __shfl_down(M,  off));
      LY = fmaxf(LY, __shfl_down(LY, off));
    }
    M = __shfl(M, 0); LY = __shfl(LY, 0);
    float contrib = (lane < 8) ? s * __expf(m - M) : 0.f;
    #pragma unroll
    for (int off = 32; off >= 1; off >>= 1) contrib += __shfl_down(contrib, off);
    const float S = __shfl(contrib, 0);

    float v = -INFINITY; int idx = -1;
    if (lane < 48) {
      const float* p = part + (size_t)(b * 8 + lane / 6) * 16;
      v   = p[4 + lane % 6];
      idx = ((const int*)p)[10 + lane % 6];
    }
    float stop = 0.f; int intop = 0;
    for (int rr = 0; rr < 6; ++rr) {
      float bv = v; int bi = idx, bl = lane;
      #pragma unroll
      for (int off = 32; off >= 1; off >>= 1) {
        const float ov = __shfl_down(bv, off);
        const int   oi = __shfl_down(bi, off);
        const int   ol = __shfl_down(bl, off);
        if (ov > bv) { bv = ov; bi = oi; bl = ol; }
      }
      bv = __shfl(bv, 0); bi = __shfl(bi, 0); bl = __shfl(bl, 0);
      stop += bv;
      if (bi == y) intop = 1;
      if (lane == bl) v = -INFINITY;
    }

    if (lane == 0) {
      const float lse = M + logf(S);
      const float loss = intop ? (13.f * lse - LY - 2.f * stop)
                               : (15.f * lse - 3.f * LY - 2.f * stop);
      atomicAdd(out, loss * (1.0f / 128.0f));
    }
    return;
  }

  // ---- em_update (block 128+i) ----
  const int t = threadIdx.x;
  if (t < B_) lbl[t] = label[t];
  __syncthreads();

  const int i = blockIdx.x - 128;
  const int y = lbl[i];
  for (int j = 0; j < i; ++j)
    if (lbl[j] == y) return;            // uniform: all threads agree

  const float alpha = 0.01f * (float)epoch[0];
  const int lane = t & 63, wave = t >> 6;

  float r[8];
  #pragma unroll
  for (int u = 0; u < 8; ++u) r[u] = em[(size_t)y * D_ + t + u * 256];

  for (int j = i; j < B_; ++j) {
    if (lbl[j] != y) continue;          // uniform branch
    const float* x = inp + j * D_;
    float ss = 0.f;
    #pragma unroll
    for (int u = 0; u < 8; ++u) {
      r[u] = alpha * r[u] + (1.f - alpha) * x[t + u * 256];
      ss += r[u] * r[u];
    }
    #pragma unroll
    for (int off = 32; off >= 1; off >>= 1) ss += __shfl_down(ss, off);
    if (lane == 0) red[wave] = ss;
    __syncthreads();
    const float inv = 1.f / sqrtf(red[0] + red[1] + red[2] + red[3]);
    #pragma unroll
    for (int u = 0; u < 8; ++u) r[u] *= inv;
    __syncthreads();                    // red[] reused next chain step
  }

  #pragma unroll
  for (int u = 0; u < 8; ++u) out_em[(size_t)y * D_ + t + u * 256] = r[u];
}

// ---------------------------------------------------------------------------
// R11 pipeline: pack_a -> fused_main (copy ∥ gemm) -> row_loss_part -> tail.
// ---------------------------------------------------------------------------
extern "C" void kernel_launch(void* const* d_in, const int* in_sizes, int n_in,
                              void* d_out, int out_size, void* d_ws, size_t ws_size,
                              hipStream_t stream) {
  const float* inp   = (const float*)d_in[0];
  const int*   label = (const int*)d_in[1];
  const float* em    = (const float*)d_in[2];
  const int*   epoch = (const int*)d_in[3];

  float* out    = (float*)d_out;
  float* out_em = out + 1;
  float* logits = (float*)d_ws;
  bf16*  apack  = (bf16*)((char*)d_ws + WS_APACK_OFF);
  float* part   = (float*)((char*)d_ws + WS_PART_OFF);

  hipMemsetAsync(d_out, 0, sizeof(float), stream);   // zero the loss slot

  pack_a        <<<dim3(128),        dim3(256), 0, stream>>>(inp, apack);
  fused_main    <<<dim3(NFUSED),     dim3(256), 0, stream>>>(em, out_em, apack, logits);
  row_loss_part <<<dim3(B_ * NCHUNK),dim3(256), 0, stream>>>(logits, label, part);
  tail          <<<dim3(256),        dim3(256), 0, stream>>>(part, label, out, inp, em, epoch, out_em);
}

// Round 13
// 117.751 us; speedup vs baseline: 1.5096x; 1.0111x over previous
//
#include <hip/hip_runtime.h>
#include <hip/hip_bf16.h>
#include <cstddef>

#define B_    128
#define D_    2048
#define C_    16522
#define BETA_INV 20.0f      // 1/0.05
#define LSTRIDE 16528       // padded logits row stride (floats)

#define NTILES 1033         // ceil(C/16)
#define NCHUNK 8
#define CHW    2066         // ceil(C/8)

#define NCOPY  2066         // copy workers in fused_main (2 per 3 blocks)
#define NFUSED 3099         // 2066 copy + 1033 gemm, interleaved 2:1

typedef __bf16 bf16;
typedef bf16  bf16x8 __attribute__((ext_vector_type(8)));
typedef float f32x4  __attribute__((ext_vector_type(4)));

// ws layout (bytes):
//   logits : [0, 8462336)                128*16528*4
//   A_pack : [8462336, 8986624)          128*2048*2  bf16 fragment-ordered
//   part   : [8986624, 9052160)          128*8*16*4  row_loss partials
#define WS_APACK_OFF 8462336
#define WS_PART_OFF  8986624

// ---------------------------------------------------------------------------
// pack_a: inputs [128,2048] fp32 -> bf16 in MFMA A-fragment order. Separate
// launch (gemm reads apack inside fused_main — intra-kernel race otherwise).
// ---------------------------------------------------------------------------
__global__ __launch_bounds__(256) void pack_a(const float* __restrict__ inp,
                                              bf16* __restrict__ ap) {
  const int tid  = blockIdx.x * 256 + threadIdx.x;   // 0..32767
  const int lane = tid & 63;
  const int ks   = (tid >> 6) & 63;
  const int mt   = tid >> 12;
  const int row  = mt * 16 + (lane & 15);
  const int col  = ks * 32 + (lane >> 4) * 8;
  const float4 v0 = *(const float4*)(inp + row * D_ + col);
  const float4 v1 = *(const float4*)(inp + row * D_ + col + 4);
  bf16x8 b;
  b[0] = (bf16)v0.x; b[1] = (bf16)v0.y; b[2] = (bf16)v0.z; b[3] = (bf16)v0.w;
  b[4] = (bf16)v1.x; b[5] = (bf16)v1.y; b[6] = (bf16)v1.z; b[7] = (bf16)v1.w;
  ((bf16x8*)ap)[tid] = b;
}

// ---------------------------------------------------------------------------
// fused_main: copy_em + gemm_logits co-resident in ONE launch (R11, 119 µs).
// R12/R13: copy stores are NON-TEMPORAL. R11's counters showed FETCH 66->134
// MB vs the serial pipeline: the concurrent working set (em 135 + out_em 135
// + logits 66 = 336 MB) exceeds the 256 MB L3, and out_em write-allocations
// evict em -> every em line re-fetched from HBM (+27 µs at the ~2.5 TB/s
// mixed-stream wall). NT on the CONTIGUOUS copy is proven safe (R4: no
// amplification, FETCH 66/WRITE 136) — unlike R3's scattered per-lane NT
// stores (+73 MB). em stays L3-resident via the copy's reads; logits writes
// stay normal (consumed by row_loss_part next).
// ---------------------------------------------------------------------------
__global__ __launch_bounds__(256, 4) void fused_main(
    const float* __restrict__ em,
    float*       __restrict__ out_em,
    const bf16*  __restrict__ ap,
    float*       __restrict__ logits)
{
  const int b  = blockIdx.x;
  const int g  = b / 3;
  const int r3 = b - g * 3;

  if (r3 < 2) {                        // ---- copy worker id = g*2+r3 ----
    const int id = g * 2 + r3;
    const int t  = threadIdx.x;
    const size_t n = (size_t)C_ * D_ / 4;          // 8,459,264 float4
    const size_t stride = (size_t)NCOPY * 512;
    for (size_t i = (size_t)id * 512 + t; i < n; i += stride) {
      const f32x4 v0 = ((const f32x4*)em)[i];
      const bool  h1 = (i + 256) < n;
      f32x4 v1 = {};
      if (h1) v1 = ((const f32x4*)em)[i + 256];
      __builtin_nontemporal_store(v0, ((f32x4*)out_em) + i);
      if (h1) __builtin_nontemporal_store(v1, ((f32x4*)out_em) + i + 256);
    }
    return;
  }

  // ---- gemm tile g (0..1032) ----
  const int tid  = threadIdx.x;
  const int lane = tid & 63;
  const int w    = tid >> 6;          // K-quarter 0..3
  const int ml   = lane & 15;
  const int quad = lane >> 4;
  const int n0   = g * 16;
  const int r    = n0 + ml;
  const bool valid = r < C_;

  const float* bp = em + (size_t)(valid ? r : 0) * D_ + quad * 8;
  const bf16x8* af = (const bf16x8*)ap;

  const int ks0 = w * 16;

  f32x4 acc[8] = {};

  f32x4 e0a = *(const f32x4*)(bp + ks0 * 32);
  f32x4 e0b = *(const f32x4*)(bp + ks0 * 32 + 4);

  #pragma unroll 3
  for (int i = 0; i < 15; ++i) {
    const int ks = ks0 + i;
    bf16x8 A0[8];
    #pragma unroll
    for (int mt = 0; mt < 8; ++mt)
      A0[mt] = af[(mt * 64 + ks) * 64 + lane];
    const f32x4 e1a = *(const f32x4*)(bp + (ks + 1) * 32);
    const f32x4 e1b = *(const f32x4*)(bp + (ks + 1) * 32 + 4);
    bf16x8 bv;
    bv[0] = (bf16)e0a[0]; bv[1] = (bf16)e0a[1]; bv[2] = (bf16)e0a[2]; bv[3] = (bf16)e0a[3];
    bv[4] = (bf16)e0b[0]; bv[5] = (bf16)e0b[1]; bv[6] = (bf16)e0b[2]; bv[7] = (bf16)e0b[3];
    #pragma unroll
    for (int mt = 0; mt < 8; ++mt)
      acc[mt] = __builtin_amdgcn_mfma_f32_16x16x32_bf16(A0[mt], bv, acc[mt], 0, 0, 0);
    e0a = e1a; e0b = e1b;
  }
  {
    const int ks = ks0 + 15;
    bf16x8 A0[8];
    #pragma unroll
    for (int mt = 0; mt < 8; ++mt)
      A0[mt] = af[(mt * 64 + ks) * 64 + lane];
    bf16x8 bv;
    bv[0] = (bf16)e0a[0]; bv[1] = (bf16)e0a[1]; bv[2] = (bf16)e0a[2]; bv[3] = (bf16)e0a[3];
    bv[4] = (bf16)e0b[0]; bv[5] = (bf16)e0b[1]; bv[6] = (bf16)e0b[2]; bv[7] = (bf16)e0b[3];
    #pragma unroll
    for (int mt = 0; mt < 8; ++mt)
      acc[mt] = __builtin_amdgcn_mfma_f32_16x16x32_bf16(A0[mt], bv, acc[mt], 0, 0, 0);
  }

  __shared__ f32x4 red[3][8][64];     // 24 KB
  if (w > 0) {
    #pragma unroll
    for (int mt = 0; mt < 8; ++mt) red[w - 1][mt][lane] = acc[mt];
  }
  __syncthreads();
  if (w == 0 && valid) {
    #pragma unroll
    for (int mt = 0; mt < 8; ++mt) {
      f32x4 a = acc[mt];
      a += red[0][mt][lane];
      a += red[1][mt][lane];
      a += red[2][mt][lane];
      #pragma unroll
      for (int reg = 0; reg < 4; ++reg) {
        const int row = mt * 16 + quad * 4 + reg;
        logits[row * LSTRIDE + r] = a[reg] * BETA_INV;
      }
    }
  }
}

// ---------------------------------------------------------------------------
// row_loss phase A: grid = 128 rows x 8 chunks. Partial online-lse + top-6
// + label logit per chunk -> part[(b*8+c)*16].
// ---------------------------------------------------------------------------
__global__ __launch_bounds__(256) void row_loss_part(
    const float* __restrict__ logits,
    const int*   __restrict__ label,
    float*       __restrict__ part)
{
  const int b = blockIdx.x >> 3;
  const int c = blockIdx.x & 7;
  const int t = threadIdx.x;
  const int lo = c * CHW;
  const int hi = (lo + CHW < C_) ? lo + CHW : C_;
  const float* row = logits + b * LSTRIDE;
  const int y = label[b];

  float m = -INFINITY, s = 0.f, ly = -INFINITY;
  float tv[6]; int ti[6];
  #pragma unroll
  for (int q = 0; q < 6; ++q) { tv[q] = -INFINITY; ti[q] = -1; }

  for (int i = lo + t; i < hi; i += 256) {
    const float v = row[i];
    if (v > m) { s = s * __expf(m - v) + 1.f; m = v; }
    else       { s += __expf(v - m); }
    if (i == y) ly = v;
    if (v > tv[5]) {
      tv[5] = v; ti[5] = i;
      #pragma unroll
      for (int q = 5; q > 0; --q)
        if (tv[q] > tv[q - 1]) {
          const float fv = tv[q]; tv[q] = tv[q - 1]; tv[q - 1] = fv;
          const int   fi = ti[q]; ti[q] = ti[q - 1]; ti[q - 1] = fi;
        }
    }
  }

  __shared__ float rm[256], rs[256];
  __shared__ float cv[1536];
  __shared__ int   ci[1536];
  __shared__ float sly;

  rm[t] = m; rs[t] = s;
  #pragma unroll
  for (int q = 0; q < 6; ++q) { cv[t * 6 + q] = tv[q]; ci[t * 6 + q] = ti[q]; }
  if (t == 0) sly = -INFINITY;
  __syncthreads();
  if (ly != -INFINITY) sly = ly;

  for (int off = 128; off >= 1; off >>= 1) {
    if (t < off) {
      const float m2 = rm[t + off], s2 = rs[t + off];
      const float M = fmaxf(rm[t], m2);
      rs[t] = rs[t] * __expf(rm[t] - M) + s2 * __expf(m2 - M);
      rm[t] = M;
    }
    __syncthreads();
  }

  if (t < 64) {   // wave 0: top-6 of 1536 candidates
    float otv[6]; int oti[6];
    for (int rr = 0; rr < 6; ++rr) {
      float bv = -INFINITY; int bi = -1, bs = -1;
      for (int u = 0; u < 24; ++u) {
        const int slot = t * 24 + u;
        const float v = cv[slot];
        if (v > bv) { bv = v; bi = ci[slot]; bs = slot; }
      }
      #pragma unroll
      for (int off = 32; off >= 1; off >>= 1) {
        const float ov = __shfl_down(bv, off);
        const int   oi = __shfl_down(bi, off);
        const int   os = __shfl_down(bs, off);
        if (ov > bv) { bv = ov; bi = oi; bs = os; }
      }
      bv = __shfl(bv, 0); bi = __shfl(bi, 0); bs = __shfl(bs, 0);
      if (bs >= t * 24 && bs < (t + 1) * 24) cv[bs] = -INFINITY;
      otv[rr] = bv; oti[rr] = bi;
    }
    if (t == 0) {
      float* p = part + (size_t)(b * 8 + c) * 16;
      p[0] = rm[0]; p[1] = rs[0]; p[2] = sly;
      #pragma unroll
      for (int q = 0; q < 6; ++q) { p[4 + q] = otv[q]; ((int*)p)[10 + q] = oti[q]; }
    }
  }
}

// ---------------------------------------------------------------------------
// tail: fused row_loss_merge (blocks 0..127) + em_update (blocks 128..255).
// ---------------------------------------------------------------------------
__global__ __launch_bounds__(256) void tail(
    const float* __restrict__ part,
    const int*   __restrict__ label,
    float*       __restrict__ out,
    const float* __restrict__ inp,
    const float* __restrict__ em,
    const int*   __restrict__ epoch,
    float*       __restrict__ out_em)
{
  __shared__ int   lbl[B_];
  __shared__ float red[4];

  if (blockIdx.x < 128) {              // ---- row_loss_merge ----
    const int b = blockIdx.x;
    const int lane = threadIdx.x;
    if (lane >= 64) return;
    const int y = label[b];

    float m = -INFINITY, s = 0.f, ly = -INFINITY;
    if (lane < 8) {
      const float* p = part + (size_t)(b * 8 + lane) * 16;
      m = p[0]; s = p[1]; ly = p[2];
    }
    float M = m, LY = ly;
    #pragma unroll
    for (int off = 32; off >= 1; off >>= 1) {
      M  = fmaxf(M,  __shfl_down(M,  off));
      LY = fmaxf(LY, __shfl_down(LY, off));
    }
    M = __shfl(M, 0); LY = __shfl(LY, 0);
    float contrib = (lane < 8) ? s * __expf(m - M) : 0.f;
    #pragma unroll
    for (int off = 32; off >= 1; off >>= 1) contrib += __shfl_down(contrib, off);
    const float S = __shfl(contrib, 0);

    float v = -INFINITY; int idx = -1;
    if (lane < 48) {
      const float* p = part + (size_t)(b * 8 + lane / 6) * 16;
      v   = p[4 + lane % 6];
      idx = ((const int*)p)[10 + lane % 6];
    }
    float stop = 0.f; int intop = 0;
    for (int rr = 0; rr < 6; ++rr) {
      float bv = v; int bi = idx, bl = lane;
      #pragma unroll
      for (int off = 32; off >= 1; off >>= 1) {
        const float ov = __shfl_down(bv, off);
        const int   oi = __shfl_down(bi, off);
        const int   ol = __shfl_down(bl, off);
        if (ov > bv) { bv = ov; bi = oi; bl = ol; }
      }
      bv = __shfl(bv, 0); bi = __shfl(bi, 0); bl = __shfl(bl, 0);
      stop += bv;
      if (bi == y) intop = 1;
      if (lane == bl) v = -INFINITY;
    }

    if (lane == 0) {
      const float lse = M + logf(S);
      const float loss = intop ? (13.f * lse - LY - 2.f * stop)
                               : (15.f * lse - 3.f * LY - 2.f * stop);
      atomicAdd(out, loss * (1.0f / 128.0f));
    }
    return;
  }

  // ---- em_update (block 128+i) ----
  const int t = threadIdx.x;
  if (t < B_) lbl[t] = label[t];
  __syncthreads();

  const int i = blockIdx.x - 128;
  const int y = lbl[i];
  for (int j = 0; j < i; ++j)
    if (lbl[j] == y) return;            // uniform: all threads agree

  const float alpha = 0.01f * (float)epoch[0];
  const int lane = t & 63, wave = t >> 6;

  float r[8];
  #pragma unroll
  for (int u = 0; u < 8; ++u) r[u] = em[(size_t)y * D_ + t + u * 256];

  for (int j = i; j < B_; ++j) {
    if (lbl[j] != y) continue;          // uniform branch
    const float* x = inp + j * D_;
    float ss = 0.f;
    #pragma unroll
    for (int u = 0; u < 8; ++u) {
      r[u] = alpha * r[u] + (1.f - alpha) * x[t + u * 256];
      ss += r[u] * r[u];
    }
    #pragma unroll
    for (int off = 32; off >= 1; off >>= 1) ss += __shfl_down(ss, off);
    if (lane == 0) red[wave] = ss;
    __syncthreads();
    const float inv = 1.f / sqrtf(red[0] + red[1] + red[2] + red[3]);
    #pragma unroll
    for (int u = 0; u < 8; ++u) r[u] *= inv;
    __syncthreads();                    // red[] reused next chain step
  }

  #pragma unroll
  for (int u = 0; u < 8; ++u) out_em[(size_t)y * D_ + t + u * 256] = r[u];
}

// ---------------------------------------------------------------------------
// R13 pipeline (= R12, resubmitted after infra failure):
// pack_a -> fused_main (copy-NT ∥ gemm) -> row_loss_part -> tail.
// ---------------------------------------------------------------------------
extern "C" void kernel_launch(void* const* d_in, const int* in_sizes, int n_in,
                              void* d_out, int out_size, void* d_ws, size_t ws_size,
                              hipStream_t stream) {
  const float* inp   = (const float*)d_in[0];
  const int*   label = (const int*)d_in[1];
  const float* em    = (const float*)d_in[2];
  const int*   epoch = (const int*)d_in[3];

  float* out    = (float*)d_out;
  float* out_em = out + 1;
  float* logits = (float*)d_ws;
  bf16*  apack  = (bf16*)((char*)d_ws + WS_APACK_OFF);
  float* part   = (float*)((char*)d_ws + WS_PART_OFF);

  hipMemsetAsync(d_out, 0, sizeof(float), stream);   // zero the loss slot

  pack_a        <<<dim3(128),        dim3(256), 0, stream>>>(inp, apack);
  fused_main    <<<dim3(NFUSED),     dim3(256), 0, stream>>>(em, out_em, apack, logits);
  row_loss_part <<<dim3(B_ * NCHUNK),dim3(256), 0, stream>>>(logits, label, part);
  tail          <<<dim3(256),        dim3(256), 0, stream>>>(part, label, out, inp, em, epoch, out_em);
}